// Round 9
// baseline (215.085 us; speedup 1.0000x reference)
//
#include <hip/hip_runtime.h>

typedef __attribute__((ext_vector_type(8))) __bf16 bf16x8;
typedef __attribute__((ext_vector_type(4))) float f32x4;

#define DI __device__ __forceinline__

// float -> bf16 bits, RNE
DI unsigned short f2bf(float x) {
  unsigned u = __float_as_uint(x);
  u += 0x7fffu + ((u >> 16) & 1u);
  return (unsigned short)(u >> 16);
}

DI bf16x8 cvt8(f32x4 lo, f32x4 hi) {
  bf16x8 r;
  r[0] = (__bf16)lo.x; r[1] = (__bf16)lo.y; r[2] = (__bf16)lo.z; r[3] = (__bf16)lo.w;
  r[4] = (__bf16)hi.x; r[5] = (__bf16)hi.y; r[6] = (__bf16)hi.z; r[7] = (__bf16)hi.w;
  return r;
}

DI float tanh_fast(float x) {
  float ax = fabsf(x);
  float e = __expf(-2.0f * ax);
  float t = (1.0f - e) / (1.0f + e);
  return x < 0.0f ? -t : t;
}

// async global->LDS, 16 B per lane. LDS dst = wave-uniform base + lane*16.
DI void glds16(const void* gptr, void* lptr) {
  __builtin_amdgcn_global_load_lds(
      (const __attribute__((address_space(1))) unsigned int*)gptr,
      (__attribute__((address_space(3))) unsigned int*)lptr, 16, 0, 0);
}

// ---------------------------------------------------------------------------
// Kernel 0: W [512(k),256(n)] fp32 -> Wt [256(n),512(k)] bf16 (B^T layout).
// (R0-proven version.)
// ---------------------------------------------------------------------------
__global__ void k_wt(const float* __restrict__ W, unsigned short* __restrict__ Wt) {
  int n = blockIdx.x;
  int t = threadIdx.x;     // 0..127
  int k = t * 4;
  ushort4 v;
  v.x = f2bf(W[(k + 0) * 256 + n]);
  v.y = f2bf(W[(k + 1) * 256 + n]);
  v.z = f2bf(W[(k + 2) * 256 + n]);
  v.w = f2bf(W[(k + 3) * 256 + n]);
  *(ushort4*)&Wt[n * 512 + k] = v;
}

// ---------------------------------------------------------------------------
// Kernel 1: projection GEMM, R0-proven version (66 us, VGPR 60, no spills).
// M=65536, K=512, N=256. Block 128x256, BK=64, 8 waves (2x4 of 64x64 tiles).
// A staged RAW FP32 via global_load_lds (32 KB/step), cvt to bf16 at fragment
// read. B staged bf16 via global_load_lds (32 KB/step). XOR chunk swizzle
// folded into the per-lane GLOBAL source address. LDS 64 KB -> 2 blocks/CU.
// ---------------------------------------------------------------------------
__global__ __launch_bounds__(512, 4) void k_proj(
    const float* __restrict__ Alt, const float* __restrict__ Art,
    const unsigned short* __restrict__ Wt, const float* __restrict__ diag,
    unsigned short* __restrict__ Olt, unsigned short* __restrict__ Ort) {
  __shared__ __align__(16) float As[128 * 64];
  __shared__ __align__(16) unsigned short Bs[256 * 64];

  int bx = blockIdx.x;              // 0..511
  bool is_lt = bx < 256;
  int m0 = (is_lt ? bx : bx - 256) * 128;
  const char* Abase = (const char*)((is_lt ? Alt : Art) + (size_t)m0 * 512);
  unsigned short* O = (is_lt ? Olt : Ort) + (size_t)m0 * 256;

  int tid  = threadIdx.x;
  int lane = tid & 63;
  int wid  = tid >> 6;              // 0..7
  int wm   = wid >> 2;              // 0..1
  int wn   = wid & 3;               // 0..3
  int l15  = lane & 15;
  int quad = lane >> 4;
  int r7   = l15 & 7;

  // glds per-lane source offsets (within a 4-row / 8-row group, k-window 0)
  int lr4 = lane >> 4, c16 = lane & 15;
  int aoff = lr4 * 2048 + ((c16 ^ lr4) << 4);          // A: row stride 2048 B
  int lr8 = lane >> 3, s8 = lane & 7;
  int boff = lr8 * 1024 + ((s8 ^ lr8) << 4);           // B: row stride 1024 B

  const char* Bbase = (const char*)Wt;
  char* AsB = (char*)As;
  char* BsB = (char*)Bs;

  f32x4 zero = {0.0f, 0.0f, 0.0f, 0.0f};
  f32x4 acc[4][4];
#pragma unroll
  for (int i = 0; i < 4; i++)
#pragma unroll
    for (int j = 0; j < 4; j++) acc[i][j] = zero;

  for (int k0 = 0; k0 < 512; k0 += 64) {
    // --- stage A (fp32): 32 insts, 4 per wave; inst j covers rows 4j..4j+3
#pragma unroll
    for (int i = 0; i < 4; i++) {
      int j = wid * 4 + i;
      glds16(Abase + (size_t)j * 8192 + (size_t)k0 * 4 + (aoff ^ ((j & 1) << 6)),
             AsB + j * 1024);
    }
    // --- stage B (bf16): 32 insts, 4 per wave; inst j covers rows 8j..8j+7
#pragma unroll
    for (int i = 0; i < 4; i++) {
      int j = wid * 4 + i;
      glds16(Bbase + (size_t)j * 8192 + (size_t)k0 * 2 + boff, BsB + j * 1024);
    }
    __syncthreads();   // drains glds (vmcnt(0) before s_barrier)

#pragma unroll
    for (int ks = 0; ks < 2; ks++) {
      bf16x8 a[4], b[4];
#pragma unroll
      for (int mt = 0; mt < 4; mt++) {
        int row = wm * 64 + mt * 16 + l15;
        int c0 = ks * 8 + quad * 2;
        f32x4 lo = *(const f32x4*)(AsB + row * 256 + (((c0    ) ^ r7) << 4));
        f32x4 hi = *(const f32x4*)(AsB + row * 256 + (((c0 + 1) ^ r7) << 4));
        a[mt] = cvt8(lo, hi);
      }
#pragma unroll
      for (int nt = 0; nt < 4; nt++) {
        int row = wn * 64 + nt * 16 + l15;
        int c = ks * 4 + quad;
        b[nt] = *(const bf16x8*)(BsB + row * 128 + ((c ^ r7) << 4));
      }
      __builtin_amdgcn_s_setprio(1);
#pragma unroll
      for (int mt = 0; mt < 4; mt++)
#pragma unroll
        for (int nt = 0; nt < 4; nt++)
          acc[mt][nt] = __builtin_amdgcn_mfma_f32_16x16x32_bf16(a[mt], b[nt], acc[mt][nt], 0, 0, 0);
      __builtin_amdgcn_s_setprio(0);
    }
    __syncthreads();   // protect LDS before next step's staging
  }

  // Epilogue: tanh, diag scale (lt only), bf16 store (row-major).
  float dscale[4];
#pragma unroll
  for (int nt = 0; nt < 4; nt++)
    dscale[nt] = is_lt ? diag[wn * 64 + nt * 16 + l15] : 1.0f;

#pragma unroll
  for (int mt = 0; mt < 4; mt++) {
#pragma unroll
    for (int r = 0; r < 4; r++) {
      int row = wm * 64 + mt * 16 + quad * 4 + r;
#pragma unroll
      for (int nt = 0; nt < 4; nt++) {
        int col = wn * 64 + nt * 16 + l15;
        O[(size_t)row * 256 + col] = f2bf(tanh_fast(acc[mt][nt][r]) * dscale[nt]);
      }
    }
  }
}

// ---------------------------------------------------------------------------
// Kernel 2: per-batch logits (lt_b @ rt_b^T, K=256) + fused no-max softmax.
// R8 structure, with the Ls LDS staging path DELETED: the a-fragment is a
// 16-B/lane contiguous read from row-major Olt (row*512 + k-byte), the
// per-block L-tile is 32 KB (L1-resident), and all 8 waves read IDENTICAL
// a-fragments -> L1 broadcast after first touch. Removes 16 MB of staged
// traffic, 8 glds/step, and the Ls LDS footprint. Rs staging unchanged.
// ---------------------------------------------------------------------------
__global__ __launch_bounds__(512, 4) void k_attn(
    const unsigned short* __restrict__ Lt, const unsigned short* __restrict__ Rt,
    float* __restrict__ Out) {
  __shared__ __align__(16) unsigned short Rs[512 * 64];   // 64 KB
  __shared__ float red[8][64];
  __shared__ float rowv[64];

  int bx = blockIdx.x;                       // 0..511
  int b  = (bx & 7) * 8 + ((bx >> 3) & 7);   // batch, XCD-co-located
  int l0 = (bx >> 6) * 64;
  const char* LbB = (const char*)(Lt + ((size_t)b * 512 + l0) * 256);
  const char* Rb  = (const char*)(Rt + (size_t)b * 512 * 256);
  float* Ob = Out + ((size_t)b * 512 + l0) * 512;

  int tid  = threadIdx.x;
  int lane = tid & 63;
  int wid  = tid >> 6;              // 0..7 -> 64-col group
  int l15  = lane & 15;
  int quad = lane >> 4;
  int r7   = l15 & 7;

  int lr8 = lane >> 3, s8 = lane & 7;
  int goff = lr8 * 512 + ((s8 ^ lr8) << 4);  // row stride 512 B (256 bf16)

  char* RsB = (char*)Rs;

  f32x4 zero = {0.0f, 0.0f, 0.0f, 0.0f};
  f32x4 acc[4][4];
#pragma unroll
  for (int i = 0; i < 4; i++)
#pragma unroll
    for (int j = 0; j < 4; j++) acc[i][j] = zero;

  for (int k0 = 0; k0 < 256; k0 += 64) {
    // Rs: 64 glds, 8 per wave
#pragma unroll
    for (int i = 0; i < 8; i++) {
      int j = wid * 8 + i;
      glds16(Rb + (size_t)j * 4096 + (size_t)k0 * 2 + goff, RsB + j * 1024);
    }
    __syncthreads();

#pragma unroll
    for (int ks = 0; ks < 2; ks++) {
      bf16x8 a[4], bb[4];
#pragma unroll
      for (int mt = 0; mt < 4; mt++) {
        int row = mt * 16 + l15;
        // direct global a-frag: 16 B contiguous at (row, k0 + ks*32 + quad*8)
        a[mt] = *(const bf16x8*)(LbB + (size_t)row * 512 + k0 * 2 + ks * 64 + quad * 16);
      }
#pragma unroll
      for (int nt = 0; nt < 4; nt++) {
        int row = wid * 64 + nt * 16 + l15;
        int c = ks * 4 + quad;
        bb[nt] = *(const bf16x8*)(RsB + row * 128 + ((c ^ r7) << 4));
      }
      __builtin_amdgcn_s_setprio(1);
#pragma unroll
      for (int mt = 0; mt < 4; mt++)
#pragma unroll
        for (int nt = 0; nt < 4; nt++)
          acc[mt][nt] = __builtin_amdgcn_mfma_f32_16x16x32_bf16(a[mt], bb[nt], acc[mt][nt], 0, 0, 0);
      __builtin_amdgcn_s_setprio(0);
    }
    __syncthreads();
  }

  // -------- softmax over the 512-wide row, no max-subtraction --------
  // (|logit| <= ~13 << 88: exp cannot overflow; identical result.)
#pragma unroll
  for (int mt = 0; mt < 4; mt++) {
#pragma unroll
    for (int r = 0; r < 4; r++) {
      float s = 0.0f;
#pragma unroll
      for (int nt = 0; nt < 4; nt++) {
        float e = __expf(acc[mt][nt][r]);
        acc[mt][nt][r] = e;
        s += e;
      }
      s += __shfl_xor(s, 1);
      s += __shfl_xor(s, 2);
      s += __shfl_xor(s, 4);
      s += __shfl_xor(s, 8);
      if (l15 == 0) red[wid][mt * 16 + quad * 4 + r] = s;
    }
  }
  __syncthreads();
  if (tid < 64) {
    float s = red[0][tid];
#pragma unroll
    for (int w = 1; w < 8; w++) s += red[w][tid];
    rowv[tid] = 1.0f / s;
  }
  __syncthreads();

#pragma unroll
  for (int mt = 0; mt < 4; mt++) {
#pragma unroll
    for (int r = 0; r < 4; r++) {
      int row = mt * 16 + quad * 4 + r;
      float inv = rowv[row];
#pragma unroll
      for (int nt = 0; nt < 4; nt++) {
        int col = wid * 64 + nt * 16 + l15;
        Ob[(size_t)row * 512 + col] = acc[mt][nt][r] * inv;
      }
    }
  }
}

// ---------------------------------------------------------------------------
extern "C" void kernel_launch(void* const* d_in, const int* in_sizes, int n_in,
                              void* d_out, int out_size, void* d_ws, size_t ws_size,
                              hipStream_t stream) {
  const float* lstm_lt = (const float*)d_in[0];   // (64,512,512)
  const float* lstm_rt = (const float*)d_in[1];   // (64,512,512)
  const float* W       = (const float*)d_in[2];   // (512,256)
  const float* diag    = (const float*)d_in[3];   // (256)
  float* out = (float*)d_out;                     // (64,512,512)

  // Workspace: Wt bf16 [256,512] | lt bf16 [32768,256] | rt bf16 [32768,256]
  unsigned short* Wt  = (unsigned short*)d_ws;
  unsigned short* Olt = (unsigned short*)((char*)d_ws + (size_t)256 * 512 * 2);
  unsigned short* Ort = Olt + (size_t)32768 * 256;

  k_wt<<<dim3(256), dim3(128), 0, stream>>>(W, Wt);
  k_proj<<<dim3(512), dim3(512), 0, stream>>>(lstm_lt, lstm_rt, Wt, diag, Olt, Ort);
  k_attn<<<dim3(512), dim3(512), 0, stream>>>(Olt, Ort, out);
}